// Round 13
// baseline (330.232 us; speedup 1.0000x reference)
//
#include <hip/hip_runtime.h>
#include <hip/hip_bf16.h>
#include <type_traits>

// ---------- types / helpers ----------
using bf16x8 = __attribute__((ext_vector_type(8))) short;   // 8 bf16 in 4 VGPRs
using f32x4  = __attribute__((ext_vector_type(4))) float;
using u16x8  = __attribute__((ext_vector_type(8))) unsigned short;
using u16x4  = __attribute__((ext_vector_type(4))) unsigned short;
using u32x4  = __attribute__((ext_vector_type(4))) unsigned int;

__device__ __forceinline__ float b2f(unsigned short u) {
    unsigned int x = ((unsigned int)u) << 16;
    return __builtin_bit_cast(float, x);
}
__device__ __forceinline__ unsigned short f2b(float f) {
    __hip_bfloat16 h = __float2bfloat16(f);   // RN
    return __builtin_bit_cast(unsigned short, h);
}

// exp2: bounded-domain scores, hardware v_exp_f32 either way
#if defined(__has_builtin)
#if __has_builtin(__builtin_amdgcn_exp2f)
#define EXP2F(x) __builtin_amdgcn_exp2f(x)
#else
#define EXP2F(x) exp2f(x)
#endif
#else
#define EXP2F(x) exp2f(x)
#endif

// async global->LDS, 16 B per lane; LDS dest is wave-uniform base + lane*16
__device__ __forceinline__ void async_copy16(const void* g, void* l) {
    __builtin_amdgcn_global_load_lds(
        (const __attribute__((address_space(1))) unsigned int*)g,
        (__attribute__((address_space(3))) unsigned int*)l, 16, 0, 0);
}

#define MFMA16(a, b, c) __builtin_amdgcn_mfma_f32_16x16x32_bf16(a, b, c, 0, 0, 0)

// raw barrier with compiler memory fence (no vmcnt/lgkmcnt drain)
#define BARRIER() do { asm volatile("" ::: "memory"); \
    __builtin_amdgcn_s_barrier(); asm volatile("" ::: "memory"); } while (0)
#define VMCNT6() asm volatile("s_waitcnt vmcnt(6)" ::: "memory")
#define VMCNT0() asm volatile("s_waitcnt vmcnt(0)" ::: "memory")

// ---------- fused f32 -> bf16 conversion for ALL 5 inputs (1 launch) ----------
// regions (float4 units): x[0,2097152) wq[..3145728) wk[..3407872)
// wv[..3670016) wo[..4718592); total 4718592 = 18432 * 256 exactly.
__global__ __launch_bounds__(256) void cvt_all(
    const float* __restrict__ x,  const float* __restrict__ wq,
    const float* __restrict__ wk, const float* __restrict__ wv,
    const float* __restrict__ wo,
    unsigned short* __restrict__ xb,  unsigned short* __restrict__ wqb,
    unsigned short* __restrict__ wkb, unsigned short* __restrict__ wvb,
    unsigned short* __restrict__ wob)
{
    int i = blockIdx.x * 256 + threadIdx.x;
    const float* s; unsigned short* d; int j;
    if (i < 2097152)      { s = x;  d = xb;  j = i; }
    else if (i < 3145728) { s = wq; d = wqb; j = i - 2097152; }
    else if (i < 3407872) { s = wk; d = wkb; j = i - 3145728; }
    else if (i < 3670016) { s = wv; d = wvb; j = i - 3407872; }
    else                  { s = wo; d = wob; j = i - 3670016; }
    float4 v = ((const float4*)s)[j];
    ushort4 o;
    o.x = f2b(v.x); o.y = f2b(v.y); o.z = f2b(v.z); o.w = f2b(v.w);
    ((ushort4*)d)[j] = o;
}

// ---------- fused QKV GEMM + RoPE, 256x256 8-phase template (T3+T4+T5) ----------
// [Q|K|V] = x @ [wq;wk;wv]^T.  M=4096, Ntot=3072, K=2048.
// Grid 16m x 12n = 192 blocks, 512 threads (8 waves), BK=64. R9-proven
// choreography. LDS 128KB: 2 dbuf x (A,B) x 256x64 bf16, 128-row halves.
// vmcnt(6) ONLY at P4/P8 (3 half-tiles in flight). RoPE fused into C-write.
__global__ __launch_bounds__(512, 2) void qkv_gemm(
    const unsigned short* __restrict__ A,    // M x 2048
    const unsigned short* __restrict__ Wq,   // 2048 x 2048
    const unsigned short* __restrict__ Wk,   // 512 x 2048
    const unsigned short* __restrict__ Wv,   // 512 x 2048
    const float* __restrict__ fc,            // 2048 x 64 cos
    const float* __restrict__ fs,            // 2048 x 64 sin
    unsigned short* __restrict__ Q,          // M x 2048
    unsigned short* __restrict__ Kk,         // M x 512
    unsigned short* __restrict__ V)          // M x 512
{
    const int K = 2048;
    __shared__ unsigned short ldsA[2][256 * 64];
    __shared__ unsigned short ldsB[2][256 * 64];

    int tid  = threadIdx.x;
    int w    = tid >> 6;           // 0..7
    int lane = tid & 63;
    int idx  = lane & 15;
    int quad = lane >> 4;
    int srow   = lane >> 3;
    int schunk = (lane & 7) ^ srow;

    int wfm = (w >> 2) * 64;       // wave m-offset within each 128-row half
    int wfn = (w & 3) * 64;        // wave n-offset

    // XCD-contiguous swizzle (192 % 8 == 0, bijective)
    int bid = (blockIdx.x & 7) * 24 + (blockIdx.x >> 3);
    int bm = bid / 12;
    int bn = bid - bm * 12;
    int m0 = bm * 256;

    const unsigned short* Bt;
    unsigned short* C;
    int Nc, n0;
    if (bn < 8)       { Bt = Wq + (size_t)bn * 256 * K;        C = Q;  Nc = 2048; n0 = bn * 256; }
    else if (bn < 10) { Bt = Wk + (size_t)(bn - 8) * 256 * K;  C = Kk; Nc = 512;  n0 = (bn - 8) * 256; }
    else              { Bt = Wv + (size_t)(bn - 10) * 256 * K; C = V;  Nc = 512;  n0 = (bn - 10) * 256; }

    const unsigned short* Ab = A + (size_t)m0 * K;

    f32x4 acc[8][4];
    #pragma unroll
    for (int mf = 0; mf < 8; ++mf)
        #pragma unroll
        for (int nf = 0; nf < 4; ++nf) acc[mf][nf] = (f32x4){0.f, 0.f, 0.f, 0.f};

    bf16x8 a[4][2], b0[2][2], b1[2][2];

    auto STAGE = [&](const unsigned short* __restrict__ G, int rb, int kc,
                     unsigned short* dst) {
        #pragma unroll
        for (int i = 0; i < 2; ++i) {
            int R = (w * 2 + i) * 8;
            async_copy16(G + (size_t)(rb + R + srow) * K + kc + schunk * 8,
                         dst + (size_t)R * 64);
        }
    };
    auto LDA = [&](int d, int mh) {
        #pragma unroll
        for (int mi = 0; mi < 4; ++mi) {
            int r = mh * 128 + wfm + mi * 16 + idx;
            #pragma unroll
            for (int ks = 0; ks < 2; ++ks)
                a[mi][ks] = *(const bf16x8*)&ldsA[d][r * 64 + (((ks * 4 + quad) ^ (r & 7)) << 3)];
        }
    };
    auto LDB0 = [&](int d, int nh) {
        #pragma unroll
        for (int nj = 0; nj < 2; ++nj) {
            int r = wfn + nh * 32 + nj * 16 + idx;
            #pragma unroll
            for (int ks = 0; ks < 2; ++ks)
                b0[nj][ks] = *(const bf16x8*)&ldsB[d][r * 64 + (((ks * 4 + quad) ^ (r & 7)) << 3)];
        }
    };
    auto LDB1 = [&](int d, int nh) {
        #pragma unroll
        for (int nj = 0; nj < 2; ++nj) {
            int r = wfn + nh * 32 + nj * 16 + idx;
            #pragma unroll
            for (int ks = 0; ks < 2; ++ks)
                b1[nj][ks] = *(const bf16x8*)&ldsB[d][r * 64 + (((ks * 4 + quad) ^ (r & 7)) << 3)];
        }
    };
    auto MM0 = [&](int mh, int nh) {
        __builtin_amdgcn_s_setprio(1);
        #pragma unroll
        for (int mi = 0; mi < 4; ++mi)
            #pragma unroll
            for (int nj = 0; nj < 2; ++nj)
                #pragma unroll
                for (int ks = 0; ks < 2; ++ks)
                    acc[mh * 4 + mi][nh * 2 + nj] =
                        MFMA16(a[mi][ks], b0[nj][ks], acc[mh * 4 + mi][nh * 2 + nj]);
        __builtin_amdgcn_s_setprio(0);
    };
    auto MM1 = [&](int mh, int nh) {
        __builtin_amdgcn_s_setprio(1);
        #pragma unroll
        for (int mi = 0; mi < 4; ++mi)
            #pragma unroll
            for (int nj = 0; nj < 2; ++nj)
                #pragma unroll
                for (int ks = 0; ks < 2; ++ks)
                    acc[mh * 4 + mi][nh * 2 + nj] =
                        MFMA16(a[mi][ks], b1[nj][ks], acc[mh * 4 + mi][nh * 2 + nj]);
        __builtin_amdgcn_s_setprio(0);
    };

    // ---- prologue: tile0 full into buf0, tile1 Alo/Blo/Bhi into buf1 ----
    STAGE(Ab, 0,   0,  &ldsA[0][0]);
    STAGE(Ab, 128, 0,  &ldsA[0][128 * 64]);
    STAGE(Bt, 0,   0,  &ldsB[0][0]);
    STAGE(Bt, 128, 0,  &ldsB[0][128 * 64]);
    STAGE(Ab, 0,   64, &ldsA[1][0]);
    STAGE(Bt, 0,   64, &ldsB[1][0]);
    STAGE(Bt, 128, 64, &ldsB[1][128 * 64]);
    VMCNT6();
    BARRIER();

    // ---- main loop: 15 iters, tiles u=2it, u+1; stages u+2, u+3 (max 31) ----
    for (int it = 0; it < 15; ++it) {
        int u = 2 * it;
        LDA(0, 0); LDB0(0, 0);
        STAGE(Ab, 128, (u + 1) * 64, &ldsA[1][128 * 64]);
        BARRIER(); MM0(0, 0); BARRIER();
        LDB1(0, 1);
        STAGE(Ab, 0, (u + 2) * 64, &ldsA[0][0]);
        BARRIER(); MM1(0, 1); BARRIER();
        LDA(0, 1);
        STAGE(Bt, 0, (u + 2) * 64, &ldsB[0][0]);
        BARRIER(); MM1(1, 1); BARRIER();
        STAGE(Bt, 128, (u + 2) * 64, &ldsB[0][128 * 64]);
        VMCNT6();
        BARRIER(); MM0(1, 0); BARRIER();
        LDA(1, 0); LDB0(1, 0);
        STAGE(Ab, 128, (u + 2) * 64, &ldsA[0][128 * 64]);
        BARRIER(); MM0(0, 0); BARRIER();
        LDB1(1, 1);
        STAGE(Ab, 0, (u + 3) * 64, &ldsA[1][0]);
        BARRIER(); MM1(0, 1); BARRIER();
        LDA(1, 1);
        STAGE(Bt, 0, (u + 3) * 64, &ldsB[1][0]);
        BARRIER(); MM1(1, 1); BARRIER();
        STAGE(Bt, 128, (u + 3) * 64, &ldsB[1][128 * 64]);
        VMCNT6();
        BARRIER(); MM0(1, 0); BARRIER();
    }

    // ---- epilogue: tiles 30 (buf0), 31 (buf1) ----
    LDA(0, 0); LDB0(0, 0);
    STAGE(Ab, 128, 31 * 64, &ldsA[1][128 * 64]);
    BARRIER(); MM0(0, 0); BARRIER();
    LDB1(0, 1);
    BARRIER(); MM1(0, 1); BARRIER();
    LDA(0, 1);
    BARRIER(); MM1(1, 1); BARRIER();
    VMCNT0();
    BARRIER(); MM0(1, 0); BARRIER();
    LDA(1, 0); LDB0(1, 0);
    BARRIER(); MM0(0, 0); BARRIER();
    LDB1(1, 1);
    BARRIER(); MM1(0, 1); BARRIER();
    LDA(1, 1);
    BARRIER(); MM1(1, 1); BARRIER();
    MM0(1, 0);

    // ---- C write with fused RoPE for Q (scale c2) and K (scale 1) ----
    bool dorope = (bn < 10);
    float osc = (bn < 8) ? 0.12752584f : 1.0f;   // (1/sqrt(128))*log2(e) for Q
    #pragma unroll
    for (int mf = 0; mf < 8; ++mf) {
        #pragma unroll
        for (int r = 0; r < 4; ++r) {
            size_t row = (size_t)(m0 + (mf >> 2) * 128 + wfm + (mf & 3) * 16 + quad * 4 + r);
            int srow_ = (int)(row & 2047) * 64;
            #pragma unroll
            for (int nf = 0; nf < 4; ++nf) {
                int col = n0 + wfn + nf * 16 + idx;
                float v = acc[mf][nf][r];
                if (dorope) {
                    float pv = __shfl_xor(v, 1);
                    int fi = srow_ + ((col & 127) >> 1);
                    float c  = fc[fi];
                    float sv = fs[fi];
                    v = (col & 1) ? (pv * sv + v * c) : (v * c - pv * sv);
                    v *= osc;
                }
                C[row * Nc + col] = f2b(v);
            }
        }
    }
}

// ---------- wo GEMM: out[M,2048] = ao[M,2048] @ wo[2048,2048]^T ----------
// Same 256x256 8-phase template as qkv (K=2048 -> identical choreography
// constants: 15-iter loop, epilogue tile 31). Grid 16m x 8n = 128 blocks,
// f32 direct output, no rope. Replaces the old 128^2 2-barrier gemm_tile
// (~620 TF): predicted ~780 TF effective at 50% CU coverage.
__global__ __launch_bounds__(512, 2) void wo_gemm(
    const unsigned short* __restrict__ A,    // M x 2048 (ao)
    const unsigned short* __restrict__ Bt,   // 2048 x 2048 (wob)
    float* __restrict__ C)                   // M x 2048 f32
{
    const int K = 2048;
    __shared__ unsigned short ldsA[2][256 * 64];
    __shared__ unsigned short ldsB[2][256 * 64];

    int tid  = threadIdx.x;
    int w    = tid >> 6;
    int lane = tid & 63;
    int idx  = lane & 15;
    int quad = lane >> 4;
    int srow   = lane >> 3;
    int schunk = (lane & 7) ^ srow;

    int wfm = (w >> 2) * 64;
    int wfn = (w & 3) * 64;

    // XCD-contiguous swizzle (128 % 8 == 0, bijective)
    int bid = (blockIdx.x & 7) * 16 + (blockIdx.x >> 3);
    int bm = bid >> 3;            // 0..15
    int bn = bid & 7;             // 0..7
    int m0 = bm * 256, n0 = bn * 256;

    const unsigned short* Ab = A  + (size_t)m0 * K;
    const unsigned short* Bb = Bt + (size_t)n0 * K;

    f32x4 acc[8][4];
    #pragma unroll
    for (int mf = 0; mf < 8; ++mf)
        #pragma unroll
        for (int nf = 0; nf < 4; ++nf) acc[mf][nf] = (f32x4){0.f, 0.f, 0.f, 0.f};

    bf16x8 a[4][2], b0[2][2], b1[2][2];

    auto STAGE = [&](const unsigned short* __restrict__ G, int rb, int kc,
                     unsigned short* dst) {
        #pragma unroll
        for (int i = 0; i < 2; ++i) {
            int R = (w * 2 + i) * 8;
            async_copy16(G + (size_t)(rb + R + srow) * K + kc + schunk * 8,
                         dst + (size_t)R * 64);
        }
    };
    auto LDA = [&](int d, int mh) {
        #pragma unroll
        for (int mi = 0; mi < 4; ++mi) {
            int r = mh * 128 + wfm + mi * 16 + idx;
            #pragma unroll
            for (int ks = 0; ks < 2; ++ks)
                a[mi][ks] = *(const bf16x8*)&ldsA[d][r * 64 + (((ks * 4 + quad) ^ (r & 7)) << 3)];
        }
    };
    auto LDB0 = [&](int d, int nh) {
        #pragma unroll
        for (int nj = 0; nj < 2; ++nj) {
            int r = wfn + nh * 32 + nj * 16 + idx;
            #pragma unroll
            for (int ks = 0; ks < 2; ++ks)
                b0[nj][ks] = *(const bf16x8*)&ldsB[d][r * 64 + (((ks * 4 + quad) ^ (r & 7)) << 3)];
        }
    };
    auto LDB1 = [&](int d, int nh) {
        #pragma unroll
        for (int nj = 0; nj < 2; ++nj) {
            int r = wfn + nh * 32 + nj * 16 + idx;
            #pragma unroll
            for (int ks = 0; ks < 2; ++ks)
                b1[nj][ks] = *(const bf16x8*)&ldsB[d][r * 64 + (((ks * 4 + quad) ^ (r & 7)) << 3)];
        }
    };
    auto MM0 = [&](int mh, int nh) {
        __builtin_amdgcn_s_setprio(1);
        #pragma unroll
        for (int mi = 0; mi < 4; ++mi)
            #pragma unroll
            for (int nj = 0; nj < 2; ++nj)
                #pragma unroll
                for (int ks = 0; ks < 2; ++ks)
                    acc[mh * 4 + mi][nh * 2 + nj] =
                        MFMA16(a[mi][ks], b0[nj][ks], acc[mh * 4 + mi][nh * 2 + nj]);
        __builtin_amdgcn_s_setprio(0);
    };
    auto MM1 = [&](int mh, int nh) {
        __builtin_amdgcn_s_setprio(1);
        #pragma unroll
        for (int mi = 0; mi < 4; ++mi)
            #pragma unroll
            for (int nj = 0; nj < 2; ++nj)
                #pragma unroll
                for (int ks = 0; ks < 2; ++ks)
                    acc[mh * 4 + mi][nh * 2 + nj] =
                        MFMA16(a[mi][ks], b1[nj][ks], acc[mh * 4 + mi][nh * 2 + nj]);
        __builtin_amdgcn_s_setprio(0);
    };

    STAGE(Ab, 0,   0,  &ldsA[0][0]);
    STAGE(Ab, 128, 0,  &ldsA[0][128 * 64]);
    STAGE(Bb, 0,   0,  &ldsB[0][0]);
    STAGE(Bb, 128, 0,  &ldsB[0][128 * 64]);
    STAGE(Ab, 0,   64, &ldsA[1][0]);
    STAGE(Bb, 0,   64, &ldsB[1][0]);
    STAGE(Bb, 128, 64, &ldsB[1][128 * 64]);
    VMCNT6();
    BARRIER();

    for (int it = 0; it < 15; ++it) {
        int u = 2 * it;
        LDA(0, 0); LDB0(0, 0);
        STAGE(Ab, 128, (u + 1) * 64, &ldsA[1][128 * 64]);
        BARRIER(); MM0(0, 0); BARRIER();
        LDB1(0, 1);
        STAGE(Ab, 0, (u + 2) * 64, &ldsA[0][0]);
        BARRIER(); MM1(0, 1); BARRIER();
        LDA(0, 1);
        STAGE(Bb, 0, (u + 2) * 64, &ldsB[0][0]);
        BARRIER(); MM1(1, 1); BARRIER();
        STAGE(Bb, 128, (u + 2) * 64, &ldsB[0][128 * 64]);
        VMCNT6();
        BARRIER(); MM0(1, 0); BARRIER();
        LDA(1, 0); LDB0(1, 0);
        STAGE(Ab, 128, (u + 2) * 64, &ldsA[0][128 * 64]);
        BARRIER(); MM0(0, 0); BARRIER();
        LDB1(1, 1);
        STAGE(Ab, 0, (u + 3) * 64, &ldsA[1][0]);
        BARRIER(); MM1(0, 1); BARRIER();
        LDA(1, 1);
        STAGE(Bb, 0, (u + 3) * 64, &ldsB[1][0]);
        BARRIER(); MM1(1, 1); BARRIER();
        STAGE(Bb, 128, (u + 3) * 64, &ldsB[1][128 * 64]);
        VMCNT6();
        BARRIER(); MM0(1, 0); BARRIER();
    }

    LDA(0, 0); LDB0(0, 0);
    STAGE(Ab, 128, 31 * 64, &ldsA[1][128 * 64]);
    BARRIER(); MM0(0, 0); BARRIER();
    LDB1(0, 1);
    BARRIER(); MM1(0, 1); BARRIER();
    LDA(0, 1);
    BARRIER(); MM1(1, 1); BARRIER();
    VMCNT0();
    BARRIER(); MM0(1, 0); BARRIER();
    LDA(1, 0); LDB0(1, 0);
    BARRIER(); MM0(0, 0); BARRIER();
    LDB1(1, 1);
    BARRIER(); MM1(0, 1); BARRIER();
    LDA(1, 1);
    BARRIER(); MM1(1, 1); BARRIER();
    MM0(1, 0);

    #pragma unroll
    for (int mf = 0; mf < 8; ++mf) {
        #pragma unroll
        for (int r = 0; r < 4; ++r) {
            size_t row = (size_t)(m0 + (mf >> 2) * 128 + wfm + (mf & 3) * 16 + quad * 4 + r);
            #pragma unroll
            for (int nf = 0; nf < 4; ++nf) {
                int col = n0 + wfn + nf * 16 + idx;
                C[row * 2048 + col] = acc[mf][nf][r];
            }
        }
    }
}

// ---------- MFMA flash attention v9: 512 blocks x 256 threads, KVBLK=64 ----------
// v8 + heavy-first block remap: first 256 bids carry p in {8..15} (nt 18..32),
// last 256 carry p in {0..7}. Pairs (bid, bid+256) share (b,h,pp) with
// p = {15-pp, pp} -> per-CU iteration sum constant at 36 under round-robin
// placement, and EVERY heavy block starts at t=0 (no backfill tail).
__global__ __launch_bounds__(256, 2) void flash_attn(
    const unsigned short* __restrict__ qg,
    const unsigned short* __restrict__ kk,
    const unsigned short* __restrict__ vv,
    unsigned short* __restrict__ out)
{
    const int S = 2048;
    int bid = blockIdx.x;
    int grp = bid >> 8;            // 0: heavy half (p 8..15), 1: light (p 0..7)
    int i_  = bid & 255;
    int b   = i_ & 1;
    int h   = (i_ >> 1) & 15;
    int pp  = i_ >> 5;             // 0..7
    int p   = grp ? pp : (15 - pp);
    int kvh = h >> 2;

    int tid  = threadIdx.x;
    int w    = tid >> 6;           // 0..3
    int lane = tid & 63;
    int idx  = lane & 15;
    int quad = lane >> 4;

    int qt  = 2 * p + (w >> 1);    // waves 0-1: tile 2p, waves 2-3: tile 2p+1
    int wq0 = qt * 64 + (w & 1) * 32;   // wave owns rows wq0..wq0+31
    int qrA = wq0 + idx;                 // group A row; group B = +16

    __shared__ unsigned short Ks[2][64 * 128];   // XOR-chunk-swizzled rows
    __shared__ unsigned short Vt[2][128 * 72];   // V^T, per-half key-permuted

    const unsigned short* kbase = kk + ((size_t)b * S * 4 + kvh) * 128;
    const unsigned short* vbase = vv + ((size_t)b * S * 4 + kvh) * 128;

    // Q fragments for both groups (B-operand): lane idx = qrow
    bf16x8 qfA[4], qfB[4];
    {
        const unsigned short* qa =
            qg + ((size_t)((b * S + wq0 + idx) * 16 + h)) * 128 + quad * 8;
        const unsigned short* qb2 =
            qg + ((size_t)((b * S + wq0 + 16 + idx) * 16 + h)) * 128 + quad * 8;
        #pragma unroll
        for (int ko = 0; ko < 4; ++ko) {
            qfA[ko] = *(const bf16x8*)(qa  + ko * 32);
            qfB[ko] = *(const bf16x8*)(qb2 + ko * 32);
        }
    }

    f32x4 accA[8], accB[8];
    #pragma unroll
    for (int n = 0; n < 8; ++n) {
        accA[n] = (f32x4){0.f, 0.f, 0.f, 0.f};
        accB[n] = (f32x4){0.f, 0.f, 0.f, 0.f};
    }
    float lsumA = 0.f, lsumB = 0.f;

    int dp = lane * 2;
    int swzslot = ((w ^ ((dp >> 3) & 3)) << 3);

    int nt = 2 * p + 2;            // 64-key iterations

    unsigned int vld[2][8];

    auto STAGE_ISSUE = [&](int t, int d) {
        #pragma unroll
        for (int i = 0; i < 4; ++i) {
            int key = w * 16 + i * 4 + (lane >> 4);
            int sc  = (lane & 15) ^ (key & 7);
            async_copy16(kbase + ((size_t)(t * 64 + key)) * 512 + sc * 8,
                         &Ks[d][(w * 16 + i * 4) * 128]);
        }
        const unsigned short* vc = vbase + ((size_t)t * 64) * 512 + dp;
        #pragma unroll
        for (int hh = 0; hh < 2; ++hh)
            #pragma unroll
            for (int ii = 0; ii < 8; ++ii) {
                int gk = hh * 32 + w * 4 + (ii >> 1) + 16 * (ii & 1);
                vld[hh][ii] = *(const unsigned int*)(vc + (size_t)gk * 512);
            }
    };
    auto STAGE_WRITE = [&](int d) {
        #pragma unroll
        for (int hh = 0; hh < 2; ++hh) {
            u16x8 lo, hi;
            #pragma unroll
            for (int ii = 0; ii < 8; ++ii) {
                lo[ii] = (unsigned short)vld[hh][ii];
                hi[ii] = (unsigned short)(vld[hh][ii] >> 16);
            }
            *(u16x8*)&Vt[d][dp * 72 + hh * 32 + swzslot]       = lo;
            *(u16x8*)&Vt[d][(dp + 1) * 72 + hh * 32 + swzslot] = hi;
        }
    };

    // ---- prologue: stage tile 0 into buf 0 ----
    STAGE_ISSUE(0, 0);
    VMCNT0();
    STAGE_WRITE(0);
    __syncthreads();

    // ---- main loop: 1 barrier / iteration ----
    for (int t = 0; t < nt; ++t) {
        int bc = t & 1;
        if (t + 1 < nt) STAGE_ISSUE(t + 1, bc ^ 1);

        if (t * 64 <= wq0 + 31) {   // tile within this wave's causal range
            f32x4 sA[4], sB[4];
            #pragma unroll
            for (int g = 0; g < 4; ++g) {
                sA[g] = (f32x4){0.f, 0.f, 0.f, 0.f};
                sB[g] = (f32x4){0.f, 0.f, 0.f, 0.f};
            }
            #pragma unroll
            for (int ko = 0; ko < 4; ++ko) {
                int ch = ((ko * 4 + quad) ^ (idx & 7)) * 8;
                #pragma unroll
                for (int g = 0; g < 4; ++g) {
                    bf16x8 kf = *(const bf16x8*)&Ks[bc][(g * 16 + idx) * 128 + ch];
                    sA[g] = MFMA16(kf, qfA[ko], sA[g]);
                    sB[g] = MFMA16(kf, qfB[ko], sB[g]);
                }
            }
            unsigned int pkA[2][4], pkB[2][4];
            if (t * 64 + 63 <= wq0) {          // full tile for all rows
                #pragma unroll
                for (int hh = 0; hh < 2; ++hh)
                    #pragma unroll
                    for (int r = 0; r < 4; ++r) {
                        float a0 = EXP2F(sA[hh * 2][r]), a1 = EXP2F(sA[hh * 2 + 1][r]);
                        float b0_ = EXP2F(sB[hh * 2][r]), b1_ = EXP2F(sB[hh * 2 + 1][r]);
                        lsumA += a0 + a1;
                        lsumB += b0_ + b1_;
                        pkA[hh][r] = (unsigned int)f2b(a0) | ((unsigned int)f2b(a1) << 16);
                        pkB[hh][r] = (unsigned int)f2b(b0_) | ((unsigned int)f2b(b1_) << 16);
                    }
            } else {                            // diagonal tile
                int LA = qrA - t * 64;
                int LB = LA + 16;
                #pragma unroll
                for (int hh = 0; hh < 2; ++hh)
                    #pragma unroll
                    for (int r = 0; r < 4; ++r) {
                        int kl = hh * 32 + quad * 4 + r;
                        float a0 = (kl      <= LA) ? EXP2F(sA[hh * 2][r]) : 0.f;
                        float a1 = (kl + 16 <= LA) ? EXP2F(sA[hh * 2 + 1][r]) : 0.f;
                        float b0_ = (kl      <= LB) ? EXP2F(sB[hh * 2][r]) : 0.f;
                        float b1_ = (kl + 16 <= LB) ? EXP2F(sB[hh * 2 + 1][r]) : 0.f;
                        lsumA += a0 + a1;
                        lsumB += b0_ + b1_;
                        pkA[hh][r] = (unsigned int)f2b(a0) | ((unsigned int)f2b(a1) << 16);
                        pkB[hh][r] = (unsigned int)f2b(b0_) | ((unsigned int)f2b(b1_) << 16);
                    }
            }
            u32x4 pA0 = {pkA[0][0], pkA[0][1], pkA[0][2], pkA[0][3]};
            u32x4 pA1 = {pkA[1][0], pkA[1][1], pkA[1][2], pkA[1][3]};
            u32x4 pB0 = {pkB[0][0], pkB[0][1], pkB[0][2], pkB[0][3]};
            u32x4 pB1 = {pkB[1][0], pkB[1][1], pkB[1][2], pkB[1][3]};
            bf16x8 pfA0 = __builtin_bit_cast(bf16x8, pA0);
            bf16x8 pfA1 = __builtin_bit_cast(bf16x8, pA1);
            bf16x8 pfB0 = __builtin_bit_cast(bf16x8, pB0);
            bf16x8 pfB1 = __builtin_bit_cast(bf16x8, pB1);
            #pragma unroll
            for (int n = 0; n < 8; ++n) {
                int rr = n * 16 + idx;
                int base = rr * 72 + ((quad ^ ((rr >> 3) & 3)) << 3);
                bf16x8 vf0 = *(const bf16x8*)&Vt[bc][base];
                bf16x8 vf1 = *(const bf16x8*)&Vt[bc][base + 32];
                accA[n] = MFMA16(vf0, pfA0, accA[n]);
                accA[n] = MFMA16(vf1, pfA1, accA[n]);
                accB[n] = MFMA16(vf0, pfB0, accB[n]);
                accB[n] = MFMA16(vf1, pfB1, accB[n]);
            }
        }

        if (t + 1 < nt) {
            VMCNT0();
            STAGE_WRITE(bc ^ 1);
        }
        __syncthreads();
    }

    // --- epilogue ---
    lsumA += __shfl_xor(lsumA, 16);
    lsumA += __shfl_xor(lsumA, 32);
    lsumB += __shfl_xor(lsumB, 16);
    lsumB += __shfl_xor(lsumB, 32);
    float invA = 1.f / lsumA;
    float invB = 1.f / lsumB;
    size_t rowA = (size_t)(b * S + wq0 + idx) * 2048 + h * 128;
    size_t rowB = rowA + (size_t)16 * 2048;
    #pragma unroll
    for (int n = 0; n < 8; ++n) {
        ushort4 oA, oB;
        oA.x = f2b(accA[n][0] * invA);
        oA.y = f2b(accA[n][1] * invA);
        oA.z = f2b(accA[n][2] * invA);
        oA.w = f2b(accA[n][3] * invA);
        oB.x = f2b(accB[n][0] * invB);
        oB.y = f2b(accB[n][1] * invB);
        oB.z = f2b(accB[n][2] * invB);
        oB.w = f2b(accB[n][3] * invB);
        *(ushort4*)&out[rowA + n * 16 + quad * 4] = oA;
        *(ushort4*)&out[rowB + n * 16 + quad * 4] = oB;
    }
}

// ---------- launch ----------
extern "C" void kernel_launch(void* const* d_in, const int* in_sizes, int n_in,
                              void* d_out, int out_size, void* d_ws, size_t ws_size,
                              hipStream_t stream)
{
    const float* x  = (const float*)d_in[0];
    const float* fc = (const float*)d_in[1];
    const float* fs = (const float*)d_in[2];
    const float* wq = (const float*)d_in[3];
    const float* wk = (const float*)d_in[4];
    const float* wv = (const float*)d_in[5];
    const float* wo = (const float*)d_in[6];
    float* out = (float*)d_out;

    const int B = 2, S = 2048, D = 2048, KV = 512;
    const int M = B * S;                 // 4096

    unsigned short* ws  = (unsigned short*)d_ws;
    unsigned short* xb  = ws;                         // 4096*2048
    unsigned short* wqb = xb  + (size_t)M * D;        // 2048*2048
    unsigned short* wkb = wqb + (size_t)D * D;        // 512*2048
    unsigned short* wvb = wkb + (size_t)KV * D;       // 512*2048
    unsigned short* wob = wvb + (size_t)KV * D;       // 2048*2048
    unsigned short* qb  = wob + (size_t)D * D;        // 4096*2048
    unsigned short* kb  = qb  + (size_t)M * D;        // 4096*512
    unsigned short* vb  = kb  + (size_t)M * KV;       // 4096*512
    unsigned short* ao  = vb  + (size_t)M * KV;       // 4096*2048

    // single fused conversion launch (all 5 inputs; 18432*256 f4 units)
    cvt_all<<<dim3(18432), dim3(256), 0, stream>>>(
        x, wq, wk, wv, wo, xb, wqb, wkb, wvb, wob);

    // fused QKV projection + RoPE: 16 m-tiles x 12 n-tiles = 192 blocks
    qkv_gemm<<<dim3(192), dim3(512), 0, stream>>>(
        xb, wqb, wkb, wvb, fc, fs, qb, kb, vb);

    // flash attention: 512 blocks x 256 threads (4 waves, KVBLK=64, heavy-first)
    flash_attn<<<dim3(512), dim3(256), 0, stream>>>(qb, kb, vb, ao);

    // wo projection: 256^2 8-phase template, 16m x 8n = 128 blocks, f32 out
    wo_gemm<<<dim3(128), dim3(512), 0, stream>>>(ao, wob, out);
}

// Round 14
// 306.963 us; speedup vs baseline: 1.0758x; 1.0758x over previous
//
#include <hip/hip_runtime.h>
#include <hip/hip_bf16.h>
#include <type_traits>

// ---------- types / helpers ----------
using bf16x8 = __attribute__((ext_vector_type(8))) short;   // 8 bf16 in 4 VGPRs
using f32x4  = __attribute__((ext_vector_type(4))) float;
using u16x8  = __attribute__((ext_vector_type(8))) unsigned short;
using u16x4  = __attribute__((ext_vector_type(4))) unsigned short;
using u32x4  = __attribute__((ext_vector_type(4))) unsigned int;

__device__ __forceinline__ float b2f(unsigned short u) {
    unsigned int x = ((unsigned int)u) << 16;
    return __builtin_bit_cast(float, x);
}
__device__ __forceinline__ unsigned short f2b(float f) {
    __hip_bfloat16 h = __float2bfloat16(f);   // RN
    return __builtin_bit_cast(unsigned short, h);
}

// exp2: bounded-domain scores, hardware v_exp_f32 either way
#if defined(__has_builtin)
#if __has_builtin(__builtin_amdgcn_exp2f)
#define EXP2F(x) __builtin_amdgcn_exp2f(x)
#else
#define EXP2F(x) exp2f(x)
#endif
#else
#define EXP2F(x) exp2f(x)
#endif

// async global->LDS, 16 B per lane; LDS dest is wave-uniform base + lane*16
__device__ __forceinline__ void async_copy16(const void* g, void* l) {
    __builtin_amdgcn_global_load_lds(
        (const __attribute__((address_space(1))) unsigned int*)g,
        (__attribute__((address_space(3))) unsigned int*)l, 16, 0, 0);
}

#define MFMA16(a, b, c) __builtin_amdgcn_mfma_f32_16x16x32_bf16(a, b, c, 0, 0, 0)

// raw barrier with compiler memory fence (no vmcnt/lgkmcnt drain)
#define BARRIER() do { asm volatile("" ::: "memory"); \
    __builtin_amdgcn_s_barrier(); asm volatile("" ::: "memory"); } while (0)
#define VMCNT6() asm volatile("s_waitcnt vmcnt(6)" ::: "memory")
#define VMCNT0() asm volatile("s_waitcnt vmcnt(0)" ::: "memory")

// ---------- fused f32 -> bf16 conversion for ALL 5 inputs (1 launch) ----------
// regions (float4 units): x[0,2097152) wq[..3145728) wk[..3407872)
// wv[..3670016) wo[..4718592); total 4718592 = 18432 * 256 exactly.
__global__ __launch_bounds__(256) void cvt_all(
    const float* __restrict__ x,  const float* __restrict__ wq,
    const float* __restrict__ wk, const float* __restrict__ wv,
    const float* __restrict__ wo,
    unsigned short* __restrict__ xb,  unsigned short* __restrict__ wqb,
    unsigned short* __restrict__ wkb, unsigned short* __restrict__ wvb,
    unsigned short* __restrict__ wob)
{
    int i = blockIdx.x * 256 + threadIdx.x;
    const float* s; unsigned short* d; int j;
    if (i < 2097152)      { s = x;  d = xb;  j = i; }
    else if (i < 3145728) { s = wq; d = wqb; j = i - 2097152; }
    else if (i < 3407872) { s = wk; d = wkb; j = i - 3145728; }
    else if (i < 3670016) { s = wv; d = wvb; j = i - 3407872; }
    else                  { s = wo; d = wob; j = i - 3670016; }
    float4 v = ((const float4*)s)[j];
    ushort4 o;
    o.x = f2b(v.x); o.y = f2b(v.y); o.z = f2b(v.z); o.w = f2b(v.w);
    ((ushort4*)d)[j] = o;
}

// ---------- fused QKV GEMM + RoPE, 256x256 8-phase template (T3+T4+T5) ----------
// [Q|K|V] = x @ [wq;wk;wv]^T.  M=4096, Ntot=3072, K=2048.
// Grid 16m x 12n = 192 blocks, 512 threads (8 waves), BK=64. R9-proven
// choreography. LDS 128KB: 2 dbuf x (A,B) x 256x64 bf16, 128-row halves.
// vmcnt(6) ONLY at P4/P8 (3 half-tiles in flight). RoPE fused into C-write.
__global__ __launch_bounds__(512, 2) void qkv_gemm(
    const unsigned short* __restrict__ A,    // M x 2048
    const unsigned short* __restrict__ Wq,   // 2048 x 2048
    const unsigned short* __restrict__ Wk,   // 512 x 2048
    const unsigned short* __restrict__ Wv,   // 512 x 2048
    const float* __restrict__ fc,            // 2048 x 64 cos
    const float* __restrict__ fs,            // 2048 x 64 sin
    unsigned short* __restrict__ Q,          // M x 2048
    unsigned short* __restrict__ Kk,         // M x 512
    unsigned short* __restrict__ V)          // M x 512
{
    const int K = 2048;
    __shared__ unsigned short ldsA[2][256 * 64];
    __shared__ unsigned short ldsB[2][256 * 64];

    int tid  = threadIdx.x;
    int w    = tid >> 6;           // 0..7
    int lane = tid & 63;
    int idx  = lane & 15;
    int quad = lane >> 4;
    int srow   = lane >> 3;
    int schunk = (lane & 7) ^ srow;

    int wfm = (w >> 2) * 64;       // wave m-offset within each 128-row half
    int wfn = (w & 3) * 64;        // wave n-offset

    // XCD-contiguous swizzle (192 % 8 == 0, bijective)
    int bid = (blockIdx.x & 7) * 24 + (blockIdx.x >> 3);
    int bm = bid / 12;
    int bn = bid - bm * 12;
    int m0 = bm * 256;

    const unsigned short* Bt;
    unsigned short* C;
    int Nc, n0;
    if (bn < 8)       { Bt = Wq + (size_t)bn * 256 * K;        C = Q;  Nc = 2048; n0 = bn * 256; }
    else if (bn < 10) { Bt = Wk + (size_t)(bn - 8) * 256 * K;  C = Kk; Nc = 512;  n0 = (bn - 8) * 256; }
    else              { Bt = Wv + (size_t)(bn - 10) * 256 * K; C = V;  Nc = 512;  n0 = (bn - 10) * 256; }

    const unsigned short* Ab = A + (size_t)m0 * K;

    f32x4 acc[8][4];
    #pragma unroll
    for (int mf = 0; mf < 8; ++mf)
        #pragma unroll
        for (int nf = 0; nf < 4; ++nf) acc[mf][nf] = (f32x4){0.f, 0.f, 0.f, 0.f};

    bf16x8 a[4][2], b0[2][2], b1[2][2];

    auto STAGE = [&](const unsigned short* __restrict__ G, int rb, int kc,
                     unsigned short* dst) {
        #pragma unroll
        for (int i = 0; i < 2; ++i) {
            int R = (w * 2 + i) * 8;
            async_copy16(G + (size_t)(rb + R + srow) * K + kc + schunk * 8,
                         dst + (size_t)R * 64);
        }
    };
    auto LDA = [&](int d, int mh) {
        #pragma unroll
        for (int mi = 0; mi < 4; ++mi) {
            int r = mh * 128 + wfm + mi * 16 + idx;
            #pragma unroll
            for (int ks = 0; ks < 2; ++ks)
                a[mi][ks] = *(const bf16x8*)&ldsA[d][r * 64 + (((ks * 4 + quad) ^ (r & 7)) << 3)];
        }
    };
    auto LDB0 = [&](int d, int nh) {
        #pragma unroll
        for (int nj = 0; nj < 2; ++nj) {
            int r = wfn + nh * 32 + nj * 16 + idx;
            #pragma unroll
            for (int ks = 0; ks < 2; ++ks)
                b0[nj][ks] = *(const bf16x8*)&ldsB[d][r * 64 + (((ks * 4 + quad) ^ (r & 7)) << 3)];
        }
    };
    auto LDB1 = [&](int d, int nh) {
        #pragma unroll
        for (int nj = 0; nj < 2; ++nj) {
            int r = wfn + nh * 32 + nj * 16 + idx;
            #pragma unroll
            for (int ks = 0; ks < 2; ++ks)
                b1[nj][ks] = *(const bf16x8*)&ldsB[d][r * 64 + (((ks * 4 + quad) ^ (r & 7)) << 3)];
        }
    };
    auto MM0 = [&](int mh, int nh) {
        __builtin_amdgcn_s_setprio(1);
        #pragma unroll
        for (int mi = 0; mi < 4; ++mi)
            #pragma unroll
            for (int nj = 0; nj < 2; ++nj)
                #pragma unroll
                for (int ks = 0; ks < 2; ++ks)
                    acc[mh * 4 + mi][nh * 2 + nj] =
                        MFMA16(a[mi][ks], b0[nj][ks], acc[mh * 4 + mi][nh * 2 + nj]);
        __builtin_amdgcn_s_setprio(0);
    };
    auto MM1 = [&](int mh, int nh) {
        __builtin_amdgcn_s_setprio(1);
        #pragma unroll
        for (int mi = 0; mi < 4; ++mi)
            #pragma unroll
            for (int nj = 0; nj < 2; ++nj)
                #pragma unroll
                for (int ks = 0; ks < 2; ++ks)
                    acc[mh * 4 + mi][nh * 2 + nj] =
                        MFMA16(a[mi][ks], b1[nj][ks], acc[mh * 4 + mi][nh * 2 + nj]);
        __builtin_amdgcn_s_setprio(0);
    };

    // ---- prologue: tile0 full into buf0, tile1 Alo/Blo/Bhi into buf1 ----
    STAGE(Ab, 0,   0,  &ldsA[0][0]);
    STAGE(Ab, 128, 0,  &ldsA[0][128 * 64]);
    STAGE(Bt, 0,   0,  &ldsB[0][0]);
    STAGE(Bt, 128, 0,  &ldsB[0][128 * 64]);
    STAGE(Ab, 0,   64, &ldsA[1][0]);
    STAGE(Bt, 0,   64, &ldsB[1][0]);
    STAGE(Bt, 128, 64, &ldsB[1][128 * 64]);
    VMCNT6();
    BARRIER();

    // ---- main loop: 15 iters, tiles u=2it, u+1; stages u+2, u+3 (max 31) ----
    for (int it = 0; it < 15; ++it) {
        int u = 2 * it;
        LDA(0, 0); LDB0(0, 0);
        STAGE(Ab, 128, (u + 1) * 64, &ldsA[1][128 * 64]);
        BARRIER(); MM0(0, 0); BARRIER();
        LDB1(0, 1);
        STAGE(Ab, 0, (u + 2) * 64, &ldsA[0][0]);
        BARRIER(); MM1(0, 1); BARRIER();
        LDA(0, 1);
        STAGE(Bt, 0, (u + 2) * 64, &ldsB[0][0]);
        BARRIER(); MM1(1, 1); BARRIER();
        STAGE(Bt, 128, (u + 2) * 64, &ldsB[0][128 * 64]);
        VMCNT6();
        BARRIER(); MM0(1, 0); BARRIER();
        LDA(1, 0); LDB0(1, 0);
        STAGE(Ab, 128, (u + 2) * 64, &ldsA[0][128 * 64]);
        BARRIER(); MM0(0, 0); BARRIER();
        LDB1(1, 1);
        STAGE(Ab, 0, (u + 3) * 64, &ldsA[1][0]);
        BARRIER(); MM1(0, 1); BARRIER();
        LDA(1, 1);
        STAGE(Bt, 0, (u + 3) * 64, &ldsB[1][0]);
        BARRIER(); MM1(1, 1); BARRIER();
        STAGE(Bt, 128, (u + 3) * 64, &ldsB[1][128 * 64]);
        VMCNT6();
        BARRIER(); MM0(1, 0); BARRIER();
    }

    // ---- epilogue: tiles 30 (buf0), 31 (buf1) ----
    LDA(0, 0); LDB0(0, 0);
    STAGE(Ab, 128, 31 * 64, &ldsA[1][128 * 64]);
    BARRIER(); MM0(0, 0); BARRIER();
    LDB1(0, 1);
    BARRIER(); MM1(0, 1); BARRIER();
    LDA(0, 1);
    BARRIER(); MM1(1, 1); BARRIER();
    VMCNT0();
    BARRIER(); MM0(1, 0); BARRIER();
    LDA(1, 0); LDB0(1, 0);
    BARRIER(); MM0(0, 0); BARRIER();
    LDB1(1, 1);
    BARRIER(); MM1(0, 1); BARRIER();
    LDA(1, 1);
    BARRIER(); MM1(1, 1); BARRIER();
    MM0(1, 0);

    // ---- C write with fused RoPE for Q (scale c2) and K (scale 1) ----
    bool dorope = (bn < 10);
    float osc = (bn < 8) ? 0.12752584f : 1.0f;   // (1/sqrt(128))*log2(e) for Q
    #pragma unroll
    for (int mf = 0; mf < 8; ++mf) {
        #pragma unroll
        for (int r = 0; r < 4; ++r) {
            size_t row = (size_t)(m0 + (mf >> 2) * 128 + wfm + (mf & 3) * 16 + quad * 4 + r);
            int srow_ = (int)(row & 2047) * 64;
            #pragma unroll
            for (int nf = 0; nf < 4; ++nf) {
                int col = n0 + wfn + nf * 16 + idx;
                float v = acc[mf][nf][r];
                if (dorope) {
                    float pv = __shfl_xor(v, 1);
                    int fi = srow_ + ((col & 127) >> 1);
                    float c  = fc[fi];
                    float sv = fs[fi];
                    v = (col & 1) ? (pv * sv + v * c) : (v * c - pv * sv);
                    v *= osc;
                }
                C[row * Nc + col] = f2b(v);
            }
        }
    }
}

// ---------- tiled GEMM: C[M,N] = A[M,K] * Bt[N,K]^T (wo projection, dbuf) ----------
// R13 post-mortem: 8-phase @128 blocks lost to this full-coverage 512-block
// structure -> reverted. Added T1 XCD swizzle (512%8==0, bijective) only.
__device__ __forceinline__ void g_stage(
    const unsigned short* __restrict__ A, const unsigned short* __restrict__ Bt,
    unsigned short* As, unsigned short* Bs,
    int k0, int K, int w, int srow, int schunk)
{
    #pragma unroll
    for (int i = 0; i < 4; ++i) {
        int cb = w * 4 + i;
        size_t goff = (size_t)(cb * 8 + srow) * K + k0 + schunk * 8;
        async_copy16(A  + goff, &As[cb * 512]);
        async_copy16(Bt + goff, &Bs[cb * 512]);
    }
}
__device__ __forceinline__ void g_compute(
    const unsigned short* As, const unsigned short* Bs,
    f32x4 (&acc)[4][4], int wm, int wn, int idx, int quad)
{
    #pragma unroll
    for (int ks = 0; ks < 2; ++ks) {
        bf16x8 af[4], bfr[4];
        #pragma unroll
        for (int mi = 0; mi < 4; ++mi) {
            int row = wm + mi * 16 + idx;
            af[mi] = *(const bf16x8*)&As[row * 64 + (((ks * 4 + quad) ^ (row & 7)) * 8)];
        }
        #pragma unroll
        for (int ni = 0; ni < 4; ++ni) {
            int row = wn + ni * 16 + idx;
            bfr[ni] = *(const bf16x8*)&Bs[row * 64 + (((ks * 4 + quad) ^ (row & 7)) * 8)];
        }
        #pragma unroll
        for (int mi = 0; mi < 4; ++mi)
            #pragma unroll
            for (int ni = 0; ni < 4; ++ni)
                acc[mi][ni] = MFMA16(af[mi], bfr[ni], acc[mi][ni]);
    }
}

template <typename OutT>
__global__ __launch_bounds__(256) void gemm_tile(
    const unsigned short* __restrict__ A,
    const unsigned short* __restrict__ Bt,
    OutT* __restrict__ C,
    int M, int N, int K)
{
    constexpr int BK = 64;
    __shared__ unsigned short As0[128 * BK];
    __shared__ unsigned short Bs0[128 * BK];
    __shared__ unsigned short As1[128 * BK];
    __shared__ unsigned short Bs1[128 * BK];

    int tid  = threadIdx.x;
    int w    = tid >> 6;
    int lane = tid & 63;
    int idx  = lane & 15;
    int quad = lane >> 4;
    int wm   = (w >> 1) * 64;
    int wn   = (w & 1) * 64;

    // T1 XCD-contiguous swizzle (grid 512, 512%8==0 -> bijective)
    int bswz = (blockIdx.x & 7) * 64 + (blockIdx.x >> 3);
    int tilesN = N / 128;
    int bm = bswz / tilesN;
    int bn = bswz - bm * tilesN;
    int m0 = bm * 128, n0 = bn * 128;

    const unsigned short* Ab = A  + (size_t)m0 * K;
    const unsigned short* Bb = Bt + (size_t)n0 * K;

    int srow   = lane >> 3;
    int schunk = (lane & 7) ^ srow;

    f32x4 acc[4][4];
    #pragma unroll
    for (int mi = 0; mi < 4; ++mi)
        #pragma unroll
        for (int ni = 0; ni < 4; ++ni) acc[mi][ni] = (f32x4){0.f, 0.f, 0.f, 0.f};

    g_stage(Ab, Bb, As0, Bs0, 0, K, w, srow, schunk);
    __syncthreads();

    for (int k0 = 0; k0 < K; k0 += 2 * BK) {
        if (k0 + BK < K)
            g_stage(Ab, Bb, As1, Bs1, k0 + BK, K, w, srow, schunk);
        g_compute(As0, Bs0, acc, wm, wn, idx, quad);
        __syncthreads();
        if (k0 + 2 * BK < K)
            g_stage(Ab, Bb, As0, Bs0, k0 + 2 * BK, K, w, srow, schunk);
        g_compute(As1, Bs1, acc, wm, wn, idx, quad);
        __syncthreads();
    }

    #pragma unroll
    for (int mi = 0; mi < 4; ++mi) {
        #pragma unroll
        for (int r = 0; r < 4; ++r) {
            size_t row = (size_t)(m0 + wm + mi * 16 + quad * 4 + r);
            #pragma unroll
            for (int ni = 0; ni < 4; ++ni) {
                int col = n0 + wn + ni * 16 + idx;
                if constexpr (std::is_same_v<OutT, float>) {
                    C[row * N + col] = acc[mi][ni][r];
                } else {
                    C[row * N + col] = f2b(acc[mi][ni][r]);
                }
            }
        }
    }
}

// ---------- MFMA flash attention v8: 512 blocks x 256 threads, KVBLK=64 ----------
// R13 post-mortem: heavy-first remap scattered (b,h) across consecutive bids
// and lost KV L2 locality -> reverted to v8 mapping (consecutive bids share
// bh; batch-complement p balances co-resident pairs).
// 4 waves; wave w: tile 2p+(w>>1), rows wq0..wq0+31 (two 16-row groups A/B
// sharing each K/V fragment read). 64-key tiles; 1 barrier/iter dbuf.
__global__ __launch_bounds__(256, 2) void flash_attn(
    const unsigned short* __restrict__ qg,
    const unsigned short* __restrict__ kk,
    const unsigned short* __restrict__ vv,
    unsigned short* __restrict__ out)
{
    const int S = 2048;
    int bid = blockIdx.x;
    int qp  = bid & 15;
    int bh  = bid >> 4;            // b*16 + h
    int h   = bh & 15;
    int b   = bh >> 4;
    int kvh = h >> 2;

    int p   = b ? (15 - qp) : qp;  // co-resident blocks sum to 34 iters

    int tid  = threadIdx.x;
    int w    = tid >> 6;           // 0..3
    int lane = tid & 63;
    int idx  = lane & 15;
    int quad = lane >> 4;

    int qt  = 2 * p + (w >> 1);    // waves 0-1: tile 2p, waves 2-3: tile 2p+1
    int wq0 = qt * 64 + (w & 1) * 32;   // wave owns rows wq0..wq0+31
    int qrA = wq0 + idx;                 // group A row; group B = +16

    __shared__ unsigned short Ks[2][64 * 128];   // XOR-chunk-swizzled rows
    __shared__ unsigned short Vt[2][128 * 72];   // V^T, per-half key-permuted

    const unsigned short* kbase = kk + ((size_t)b * S * 4 + kvh) * 128;
    const unsigned short* vbase = vv + ((size_t)b * S * 4 + kvh) * 128;

    // Q fragments for both groups (B-operand): lane idx = qrow
    bf16x8 qfA[4], qfB[4];
    {
        const unsigned short* qa =
            qg + ((size_t)((b * S + wq0 + idx) * 16 + h)) * 128 + quad * 8;
        const unsigned short* qb2 =
            qg + ((size_t)((b * S + wq0 + 16 + idx) * 16 + h)) * 128 + quad * 8;
        #pragma unroll
        for (int ko = 0; ko < 4; ++ko) {
            qfA[ko] = *(const bf16x8*)(qa  + ko * 32);
            qfB[ko] = *(const bf16x8*)(qb2 + ko * 32);
        }
    }

    f32x4 accA[8], accB[8];
    #pragma unroll
    for (int n = 0; n < 8; ++n) {
        accA[n] = (f32x4){0.f, 0.f, 0.f, 0.f};
        accB[n] = (f32x4){0.f, 0.f, 0.f, 0.f};
    }
    float lsumA = 0.f, lsumB = 0.f;

    int dp = lane * 2;
    int swzslot = ((w ^ ((dp >> 3) & 3)) << 3);

    int nt = 2 * p + 2;            // 64-key iterations

    unsigned int vld[2][8];

    auto STAGE_ISSUE = [&](int t, int d) {
        #pragma unroll
        for (int i = 0; i < 4; ++i) {
            int key = w * 16 + i * 4 + (lane >> 4);
            int sc  = (lane & 15) ^ (key & 7);
            async_copy16(kbase + ((size_t)(t * 64 + key)) * 512 + sc * 8,
                         &Ks[d][(w * 16 + i * 4) * 128]);
        }
        const unsigned short* vc = vbase + ((size_t)t * 64) * 512 + dp;
        #pragma unroll
        for (int hh = 0; hh < 2; ++hh)
            #pragma unroll
            for (int ii = 0; ii < 8; ++ii) {
                int gk = hh * 32 + w * 4 + (ii >> 1) + 16 * (ii & 1);
                vld[hh][ii] = *(const unsigned int*)(vc + (size_t)gk * 512);
            }
    };
    auto STAGE_WRITE = [&](int d) {
        #pragma unroll
        for (int hh = 0; hh < 2; ++hh) {
            u16x8 lo, hi;
            #pragma unroll
            for (int ii = 0; ii < 8; ++ii) {
                lo[ii] = (unsigned short)vld[hh][ii];
                hi[ii] = (unsigned short)(vld[hh][ii] >> 16);
            }
            *(u16x8*)&Vt[d][dp * 72 + hh * 32 + swzslot]       = lo;
            *(u16x8*)&Vt[d][(dp + 1) * 72 + hh * 32 + swzslot] = hi;
        }
    };

    // ---- prologue: stage tile 0 into buf 0 ----
    STAGE_ISSUE(0, 0);
    VMCNT0();
    STAGE_WRITE(0);
    __syncthreads();

    // ---- main loop: 1 barrier / iteration ----
    for (int t = 0; t < nt; ++t) {
        int bc = t & 1;
        if (t + 1 < nt) STAGE_ISSUE(t + 1, bc ^ 1);

        if (t * 64 <= wq0 + 31) {   // tile within this wave's causal range
            f32x4 sA[4], sB[4];
            #pragma unroll
            for (int g = 0; g < 4; ++g) {
                sA[g] = (f32x4){0.f, 0.f, 0.f, 0.f};
                sB[g] = (f32x4){0.f, 0.f, 0.f, 0.f};
            }
            #pragma unroll
            for (int ko = 0; ko < 4; ++ko) {
                int ch = ((ko * 4 + quad) ^ (idx & 7)) * 8;
                #pragma unroll
                for (int g = 0; g < 4; ++g) {
                    bf16x8 kf = *(const bf16x8*)&Ks[bc][(g * 16 + idx) * 128 + ch];
                    sA[g] = MFMA16(kf, qfA[ko], sA[g]);
                    sB[g] = MFMA16(kf, qfB[ko], sB[g]);
                }
            }
            unsigned int pkA[2][4], pkB[2][4];
            if (t * 64 + 63 <= wq0) {          // full tile for all rows
                #pragma unroll
                for (int hh = 0; hh < 2; ++hh)
                    #pragma unroll
                    for (int r = 0; r < 4; ++r) {
                        float a0 = EXP2F(sA[hh * 2][r]), a1 = EXP2F(sA[hh * 2 + 1][r]);
                        float b0_ = EXP2F(sB[hh * 2][r]), b1_ = EXP2F(sB[hh * 2 + 1][r]);
                        lsumA += a0 + a1;
                        lsumB += b0_ + b1_;
                        pkA[hh][r] = (unsigned int)f2b(a0) | ((unsigned int)f2b(a1) << 16);
                        pkB[hh][r] = (unsigned int)f2b(b0_) | ((unsigned int)f2b(b1_) << 16);
                    }
            } else {                            // diagonal tile
                int LA = qrA - t * 64;
                int LB = LA + 16;
                #pragma unroll
                for (int hh = 0; hh < 2; ++hh)
                    #pragma unroll
                    for (int r = 0; r < 4; ++r) {
                        int kl = hh * 32 + quad * 4 + r;
                        float a0 = (kl      <= LA) ? EXP2F(sA[hh * 2][r]) : 0.f;
                        float a1 = (kl + 16 <= LA) ? EXP2F(sA[hh * 2 + 1][r]) : 0.f;
                        float b0_ = (kl      <= LB) ? EXP2F(sB[hh * 2][r]) : 0.f;
                        float b1_ = (kl + 16 <= LB) ? EXP2F(sB[hh * 2 + 1][r]) : 0.f;
                        lsumA += a0 + a1;
                        lsumB += b0_ + b1_;
                        pkA[hh][r] = (unsigned int)f2b(a0) | ((unsigned int)f2b(a1) << 16);
                        pkB[hh][r] = (unsigned int)f2b(b0_) | ((unsigned int)f2b(b1_) << 16);
                    }
            }
            u32x4 pA0 = {pkA[0][0], pkA[0][1], pkA[0][2], pkA[0][3]};
            u32x4 pA1 = {pkA[1][0], pkA[1][1], pkA[1][2], pkA[1][3]};
            u32x4 pB0 = {pkB[0][0], pkB[0][1], pkB[0][2], pkB[0][3]};
            u32x4 pB1 = {pkB[1][0], pkB[1][1], pkB[1][2], pkB[1][3]};
            bf16x8 pfA0 = __builtin_bit_cast(bf16x8, pA0);
            bf16x8 pfA1 = __builtin_bit_cast(bf16x8, pA1);
            bf16x8 pfB0 = __builtin_bit_cast(bf16x8, pB0);
            bf16x8 pfB1 = __builtin_bit_cast(bf16x8, pB1);
            #pragma unroll
            for (int n = 0; n < 8; ++n) {
                int rr = n * 16 + idx;
                int base = rr * 72 + ((quad ^ ((rr >> 3) & 3)) << 3);
                bf16x8 vf0 = *(const bf16x8*)&Vt[bc][base];
                bf16x8 vf1 = *(const bf16x8*)&Vt[bc][base + 32];
                accA[n] = MFMA16(vf0, pfA0, accA[n]);
                accA[n] = MFMA16(vf1, pfA1, accA[n]);
                accB[n] = MFMA16(vf0, pfB0, accB[n]);
                accB[n] = MFMA16(vf1, pfB1, accB[n]);
            }
        }

        if (t + 1 < nt) {
            VMCNT0();
            STAGE_WRITE(bc ^ 1);
        }
        __syncthreads();
    }

    // --- epilogue ---
    lsumA += __shfl_xor(lsumA, 16);
    lsumA += __shfl_xor(lsumA, 32);
    lsumB += __shfl_xor(lsumB, 16);
    lsumB += __shfl_xor(lsumB, 32);
    float invA = 1.f / lsumA;
    float invB = 1.f / lsumB;
    size_t rowA = (size_t)(b * S + wq0 + idx) * 2048 + h * 128;
    size_t rowB = rowA + (size_t)16 * 2048;
    #pragma unroll
    for (int n = 0; n < 8; ++n) {
        ushort4 oA, oB;
        oA.x = f2b(accA[n][0] * invA);
        oA.y = f2b(accA[n][1] * invA);
        oA.z = f2b(accA[n][2] * invA);
        oA.w = f2b(accA[n][3] * invA);
        oB.x = f2b(accB[n][0] * invB);
        oB.y = f2b(accB[n][1] * invB);
        oB.z = f2b(accB[n][2] * invB);
        oB.w = f2b(accB[n][3] * invB);
        *(ushort4*)&out[rowA + n * 16 + quad * 4] = oA;
        *(ushort4*)&out[rowB + n * 16 + quad * 4] = oB;
    }
}

// ---------- launch ----------
extern "C" void kernel_launch(void* const* d_in, const int* in_sizes, int n_in,
                              void* d_out, int out_size, void* d_ws, size_t ws_size,
                              hipStream_t stream)
{
    const float* x  = (const float*)d_in[0];
    const float* fc = (const float*)d_in[1];
    const float* fs = (const float*)d_in[2];
    const float* wq = (const float*)d_in[3];
    const float* wk = (const float*)d_in[4];
    const float* wv = (const float*)d_in[5];
    const float* wo = (const float*)d_in[6];
    float* out = (float*)d_out;

    const int B = 2, S = 2048, D = 2048, KV = 512;
    const int M = B * S;                 // 4096

    unsigned short* ws  = (unsigned short*)d_ws;
    unsigned short* xb  = ws;                         // 4096*2048
    unsigned short* wqb = xb  + (size_t)M * D;        // 2048*2048
    unsigned short* wkb = wqb + (size_t)D * D;        // 512*2048
    unsigned short* wvb = wkb + (size_t)KV * D;       // 512*2048
    unsigned short* wob = wvb + (size_t)KV * D;       // 2048*2048
    unsigned short* qb  = wob + (size_t)D * D;        // 4096*2048
    unsigned short* kb  = qb  + (size_t)M * D;        // 4096*512
    unsigned short* vb  = kb  + (size_t)M * KV;       // 4096*512
    unsigned short* ao  = vb  + (size_t)M * KV;       // 4096*2048

    // single fused conversion launch (all 5 inputs; 18432*256 f4 units)
    cvt_all<<<dim3(18432), dim3(256), 0, stream>>>(
        x, wq, wk, wv, wo, xb, wqb, wkb, wvb, wob);

    // fused QKV projection + RoPE: 16 m-tiles x 12 n-tiles = 192 blocks
    qkv_gemm<<<dim3(192), dim3(512), 0, stream>>>(
        xb, wqb, wkb, wvb, fc, fs, qb, kb, vb);

    // flash attention: 512 blocks x 256 threads (4 waves, KVBLK=64)
    flash_attn<<<dim3(512), dim3(256), 0, stream>>>(qb, kb, vb, ao);

    // wo projection: full-coverage 128^2 dbuf, 512 blocks + XCD swizzle
    gemm_tile<float><<<dim3((M / 128) * (D / 128)), dim3(256), 0, stream>>>(ao, wob, out, M, D, D);
}